// Round 2
// baseline (1084.313 us; speedup 1.0000x reference)
//
#include <hip/hip_runtime.h>
#include <cstdint>
#include <cstddef>

#define N_SENT 65536
#define DIMS   2304
#define NBAG   4096
#define NCLS   53
#define PROW   56   // probs row stride in floats

typedef __attribute__((ext_vector_type(8))) float f32x8;

// ---------------- ws layout (bytes) ----------------
// Wcs    : [8][DIMS][8] float  @ 0          (589824)   class-slice-major W
// probs  : [N_SENT][PROW]      @ 589824     (14680064)
// lp     : [N_SENT]            @ 15269888   (262144)
// tcls   : [N_SENT]            @ 15532032   (262144)
// bias64 : [64]                @ 15794176   (256)

__device__ __forceinline__ void async_copy16(const float* g, float* l) {
    __builtin_amdgcn_global_load_lds(
        (const __attribute__((address_space(1))) unsigned int*)g,
        (__attribute__((address_space(3))) unsigned int*)l,
        16, 0, 0);
}

// ------------- kernel 0: build Wcs [w][k][c]=W[8w+c][k], tcls, bias64 -------------
__global__ void prep_kernel(const float* __restrict__ W,
                            const int* __restrict__ scope,
                            const int* __restrict__ label,
                            const float* __restrict__ b,
                            float* __restrict__ Wcs,
                            int* __restrict__ tcls,
                            float* __restrict__ bias64) {
    int gid = blockIdx.x * 256 + threadIdx.x;
    if (gid < 8 * DIMS * 8) {                       // 147456 = 576 blocks
        int w = gid / (DIMS * 8);
        int r = gid % (DIMS * 8);
        int k = r >> 3;
        int c = r & 7;
        int cls = 8 * w + c;
        Wcs[gid] = (cls < NCLS) ? W[(size_t)cls * DIMS + k] : 0.0f;
    } else {
        int id = gid - 8 * DIMS * 8;
        if (id < NBAG) {
            int s = scope[id], e = scope[id + 1];
            int lb = label[id];
            for (int j = s; j < e; ++j) tcls[j] = lb;
        } else if (id < NBAG + 64) {
            int c = id - NBAG;
            bias64[c] = (c < NCLS) ? b[c] : -1e30f;
        }
    }
}

// ------------- kernel 1: logits -> softmax -> probs + lp -------------
// 512 threads (8 waves), grid 256. Block tile: 256 sentences x 64 classes.
// Wave w owns classes 8w..8w+7 (W via wave-uniform loads, no LDS).
// Lane L owns sentence rows L+64i (i<4). LDS holds only the A tile:
// layout [slab=KC/4][row=256][4 dwords], double-buffered (2 x 32 KB).
__launch_bounds__(512, 2)
__global__ void logits_kernel(const float* __restrict__ reps,
                              const float* __restrict__ Wcs,
                              const float* __restrict__ bias64,
                              const int* __restrict__ tcls,
                              float* __restrict__ probs,
                              float* __restrict__ lp) {
    __shared__ float lds[2][8192];   // 65536 B total

    const int tid = threadIdx.x;
    const int L   = tid & 63;
    const int w   = __builtin_amdgcn_readfirstlane(tid >> 6);   // 0..7, uniform
    const int m0  = blockIdx.x * 256;

    float acc[4][8];
#pragma unroll
    for (int i = 0; i < 4; ++i)
#pragma unroll
        for (int c = 0; c < 8; ++c) acc[i][c] = 0.0f;

    const float* wbase = Wcs + (size_t)w * DIMS * 8;

    // staging: 32 instrs/block = 4/wave. id=w*4+s -> q=id>>3 (row-quarter), c4=id&7 (k-slab)
    // gptr = reps[(m0 + q*64 + L)*DIMS + kc + c4*4]; dst = buf + c4*1024 + q*256 dwords
    auto stage = [&](int t, int buf) {
#pragma unroll
        for (int s = 0; s < 4; ++s) {
            int id = w * 4 + s;
            int q  = id >> 3;
            int c4 = id & 7;
            const float* g = reps + (size_t)(m0 + q * 64 + L) * DIMS + t * 32 + c4 * 4;
            float* l = &lds[buf][c4 * 1024 + q * 256];
            async_copy16(g, l);
        }
    };

    stage(0, 0);

    for (int t = 0; t < 72; ++t) {
        __syncthreads();                 // buf[t&1] staged; prev compute done
        if (t + 1 < 72) stage(t + 1, (t + 1) & 1);
        const float* lb = lds[t & 1];
        const float* wk = wbase + (size_t)t * 32 * 8;
#pragma unroll
        for (int kk = 0; kk < 32; kk += 4) {
            f32x8 wv0 = *(const f32x8*)(wk + (kk + 0) * 8);
            f32x8 wv1 = *(const f32x8*)(wk + (kk + 1) * 8);
            f32x8 wv2 = *(const f32x8*)(wk + (kk + 2) * 8);
            f32x8 wv3 = *(const f32x8*)(wk + (kk + 3) * 8);
            const float* slab = lb + (kk >> 2) * 1024;
#pragma unroll
            for (int i = 0; i < 4; ++i) {
                float4 rv = *(const float4*)&slab[(L + 64 * i) * 4];
#pragma unroll
                for (int c = 0; c < 8; ++c) {
                    acc[i][c] = fmaf(rv.x, wv0[c], acc[i][c]);
                    acc[i][c] = fmaf(rv.y, wv1[c], acc[i][c]);
                    acc[i][c] = fmaf(rv.z, wv2[c], acc[i][c]);
                    acc[i][c] = fmaf(rv.w, wv3[c], acc[i][c]);
                }
            }
        }
    }

    // ---- epilogue: bias, cross-wave softmax via tiny LDS reductions ----
    __syncthreads();                      // all rv reads of last chunk done
    float* red = &lds[0][0];              // reuse as [256][8]

    f32x8 bv = *(const f32x8*)(bias64 + 8 * w);

    float mx[4];
#pragma unroll
    for (int i = 0; i < 4; ++i) {
        float pm = -1e38f;
#pragma unroll
        for (int c = 0; c < 8; ++c) {
            acc[i][c] += bv[c];           // pad classes: bias=-1e30 -> never max
            pm = fmaxf(pm, acc[i][c]);
        }
        red[(L + 64 * i) * 8 + w] = pm;
    }
    __syncthreads();
#pragma unroll
    for (int i = 0; i < 4; ++i) {
        const float* r8 = &red[(L + 64 * i) * 8];
        float m01 = fmaxf(r8[0], r8[1]), m23 = fmaxf(r8[2], r8[3]);
        float m45 = fmaxf(r8[4], r8[5]), m67 = fmaxf(r8[6], r8[7]);
        mx[i] = fmaxf(fmaxf(m01, m23), fmaxf(m45, m67));
    }
    __syncthreads();                      // done reading maxes
    float ps[4];
#pragma unroll
    for (int i = 0; i < 4; ++i) {
        float s = 0.0f;
#pragma unroll
        for (int c = 0; c < 8; ++c) {
            acc[i][c] = __expf(acc[i][c] - mx[i]);
            s += acc[i][c];
        }
        red[(L + 64 * i) * 8 + w] = s;
    }
    __syncthreads();
#pragma unroll
    for (int i = 0; i < 4; ++i) {
        const float* r8 = &red[(L + 64 * i) * 8];
        float s = ((r8[0] + r8[1]) + (r8[2] + r8[3])) + ((r8[4] + r8[5]) + (r8[6] + r8[7]));
        float inv = 1.0f / s;
        int m = m0 + L + 64 * i;
        float* prow = probs + (size_t)m * PROW;
        float4 p0 = make_float4(acc[i][0] * inv, acc[i][1] * inv, acc[i][2] * inv, acc[i][3] * inv);
        float4 p1 = make_float4(acc[i][4] * inv, acc[i][5] * inv, acc[i][6] * inv, acc[i][7] * inv);
        if (w < 6) {
            *(float4*)(prow + 8 * w)     = p0;
            *(float4*)(prow + 8 * w + 4) = p1;
        } else if (w == 6) {
            *(float4*)(prow + 48) = p0;
            prow[52] = p1.x;
        }
        int tlab = tcls[m];
        if ((tlab >> 3) == w) {
            int c = tlab & 7;
            float v = acc[i][0];
            v = (c == 1) ? acc[i][1] : v;
            v = (c == 2) ? acc[i][2] : v;
            v = (c == 3) ? acc[i][3] : v;
            v = (c == 4) ? acc[i][4] : v;
            v = (c == 5) ? acc[i][5] : v;
            v = (c == 6) ? acc[i][6] : v;
            v = (c == 7) ? acc[i][7] : v;
            lp[m] = v * inv;
        }
    }
}

// ------------- kernel 2: per-bag first-argmax over lp, gather probs row -------------
__global__ void select_kernel(const int* __restrict__ scope,
                              const float* __restrict__ lp,
                              const float* __restrict__ probs,
                              float* __restrict__ out) {
    int wave = threadIdx.x >> 6;
    int lane = threadIdx.x & 63;
    int bag  = blockIdx.x * 4 + wave;
    int s = scope[bag], e = scope[bag + 1];

    float bvv = -1e38f;
    int   bj  = 0x7fffffff;
    for (int j = s + lane; j < e; j += 64) {
        float v = lp[j];
        if (v > bvv) { bvv = v; bj = j; }   // strict > keeps first max per lane
    }
#pragma unroll
    for (int off = 1; off < 64; off <<= 1) {
        float ov = __shfl_xor(bvv, off, 64);
        int   oj = __shfl_xor(bj, off, 64);
        if (ov > bvv || (ov == bvv && oj < bj)) { bvv = ov; bj = oj; }
    }
    if (lane < NCLS)
        out[(size_t)bag * NCLS + lane] = probs[(size_t)bj * PROW + lane];
}

extern "C" void kernel_launch(void* const* d_in, const int* in_sizes, int n_in,
                              void* d_out, int out_size, void* d_ws, size_t ws_size,
                              hipStream_t stream) {
    const float* reps  = (const float*)d_in[0];
    const int*   scope = (const int*)d_in[1];
    const int*   label = (const int*)d_in[2];
    const float* W     = (const float*)d_in[3];
    const float* b     = (const float*)d_in[4];
    float*       out   = (float*)d_out;

    char* ws = (char*)d_ws;
    float* Wcs    = (float*)(ws);
    float* probs  = (float*)(ws + 589824);
    float* lp     = (float*)(ws + 589824 + 14680064);
    int*   tcls   = (int*)(ws + 589824 + 14680064 + 262144);
    float* bias64 = (float*)(ws + 589824 + 14680064 + 262144 + 262144);

    prep_kernel<<<593, 256, 0, stream>>>(W, scope, label, b, Wcs, tcls, bias64);
    logits_kernel<<<256, 512, 0, stream>>>(reps, Wcs, bias64, tcls, probs, lp);
    select_kernel<<<NBAG / 4, 256, 0, stream>>>(scope, lp, probs, out);
}